// Round 30
// baseline (50.466 us; speedup 1.0000x reference)
//
#include <hip/hip_runtime.h>

typedef __attribute__((ext_vector_type(4))) float f32x4;
typedef __attribute__((ext_vector_type(8))) short bf16x8;

typedef const __attribute__((address_space(1))) float* gas1p;
typedef __attribute__((address_space(3))) float* las3p;

__device__ __forceinline__ short bf16_rne(float f) {
    unsigned int u = __float_as_uint(f);
    u += 0x7FFFu + ((u >> 16) & 1u);
    return (short)(u >> 16);
}

// G=16, in_g=out_g=64. rows-per-group = 32768, total rows = 524288.
// Row r: 64 contiguous floats of x; group g = r>>15.
// out[(g*64+o)*32768 + (r & 32767)].
// Wave: 64 consecutive rows = 4 tiles of 16 rows. 8192 waves = 2048 blocks x 4.
// NUMERICS: R1's validated path (absmax 0.031): A = bf16(xhat*gamma+beta),
// B = bf16(W) from global loads, bias in fp32 epilogue.
// R28: 2-slot wave-private LDS DMA pipeline (8 KB/wave, 32 KB/block ->
// occupancy ceiling 37.5%->50%) + W-FIRST issue order (R27 issued DMAs first,
// so W-consumption waits drained all DMAs - vmcnt FIFO; now preamble loads
// are OLDER than DMAs and their waits leave x tiles in flight).
// FIFO schedule: [preamble ~28 loads][t0 4][t1 4] loop{ t=0: vmcnt(4) read
// s0, lgkmcnt(0), issue t2->s0; t=1: vmcnt(4) read s1, lgkmcnt(0), issue
// t3->s1; t=2: vmcnt(4) read s0; t=3: vmcnt(0) read s1 }.
// XOR swizzle cl^(row&7): DMA writes linear (m104), reads recover sector.
// Bank conflicts measured negligible in R27 (~1us total).
// STORES (FROZEN): defer vout[4][4]; per channel FULL 256-B span, 4 adjacent
// `global_store_dwordx4 sc0 sc1 nt` at KERNEL END (raw asm only safe there -
// R19). sc1+nt: WRITE = exactly |out| (R18/R22/R25).
// FAILED AVENUES (do not retry): persistence (R11/R16/R17); 2-deep REGISTER
// prefetch (R13/R14); channel-split (R15); LDS out-epilogue (R8); LDS
// W-staging (R24 numerics); gamma-fold (R2 numerics); nt w/o sc1 (R4/R6/R7);
// asm stores mid-loop (R19); per-tile buffer stores (R22);
// launch_bounds(256,8) (R23 spills); sc0 L3-bypass (R25 neutral).

__global__ __launch_bounds__(256, 2)
void gln_mfma_kernel(const float* __restrict__ x,
                     const float* __restrict__ gamma,
                     const float* __restrict__ beta,
                     const float* __restrict__ W,
                     const float* __restrict__ bias,
                     float* __restrict__ out)
{
    __shared__ __align__(16) float xlds[4][2][1024];   // 4 waves x 2 slots x 4KB

    const int tid  = threadIdx.x;
    const int lane = tid & 63;
    const int wv   = tid >> 6;
    const int w    = blockIdx.x * 4 + wv;            // 0..8191
    const int g    = w >> 9;                         // 16 groups, 512 waves each
    const int rr0  = (w & 511) << 6;                 // row-in-group base (64 rows)

    const int l15 = lane & 15;
    const int l4  = lane >> 4;      // 0..3
    const int ks  = l4 * 8;         // k-slice base within a 32-wide K chunk

    const float* xg = x   + (size_t)g * 32768 * 64;
    float* outg     = out + (size_t)g * 64 * 32768;

    // issue tile t into slot s: 4 global_load_lds (w16), LDS linear by lane,
    // global source pre-swizzled so readback sector c is at stored c^(row&7).
    auto issue_tile = [&](int t, int s) {
        const float* tb = xg + (size_t)(rr0 + t * 16) * 64;
        #pragma unroll
        for (int j = 0; j < 4; ++j) {
            const int p   = j * 64 + lane;           // linear 16B-sector 0..255
            const int row = p >> 4;
            const int cl  = p & 15;
            const float* src = tb + row * 64 + ((cl ^ (row & 7)) << 2);
            __builtin_amdgcn_global_load_lds((gas1p)src,
                (las3p)(&xlds[wv][s][j * 256]), 16, 0, 0);
        }
    };

    // ---- 1) preamble loads FIRST (oldest in vmcnt FIFO: their consumption
    //      waits will not drain the younger x DMAs) ----
    bf16x8 bfrag[4][2];
    {
        const float* Wg = W + (size_t)(g * 64) * 64;
        #pragma unroll
        for (int ot = 0; ot < 4; ++ot) {
            const float* wrow = Wg + (size_t)(ot * 16 + l15) * 64;
            #pragma unroll
            for (int kc = 0; kc < 2; ++kc) {
                f32x4 w0 = *(const f32x4*)(wrow + kc * 32 + ks);
                f32x4 w1 = *(const f32x4*)(wrow + kc * 32 + ks + 4);
                bf16x8 f;
                #pragma unroll
                for (int j = 0; j < 4; ++j) { f[j] = bf16_rne(w0[j]); f[j + 4] = bf16_rne(w1[j]); }
                bfrag[ot][kc] = f;
            }
        }
    }

    float gk[16], bk[16];
    {
        const float* gp = gamma + g * 64;
        const float* bp = beta  + g * 64;
        #pragma unroll
        for (int kc = 0; kc < 2; ++kc) {
            f32x4 g0 = *(const f32x4*)(gp + kc * 32 + ks);
            f32x4 g1 = *(const f32x4*)(gp + kc * 32 + ks + 4);
            f32x4 b0 = *(const f32x4*)(bp + kc * 32 + ks);
            f32x4 b1 = *(const f32x4*)(bp + kc * 32 + ks + 4);
            #pragma unroll
            for (int j = 0; j < 4; ++j) {
                gk[kc * 8 + j] = g0[j]; gk[kc * 8 + 4 + j] = g1[j];
                bk[kc * 8 + j] = b0[j]; bk[kc * 8 + 4 + j] = b1[j];
            }
        }
    }

    float bo[4];
    #pragma unroll
    for (int ot = 0; ot < 4; ++ot) bo[ot] = bias[g * 64 + ot * 16 + l15];

    // ---- 2) issue x tiles 0,1 (younger than every preamble load) ----
    issue_tile(0, 0);
    issue_tile(1, 1);
    __builtin_amdgcn_sched_barrier(0);

    f32x4 vout[4][4];                   // [tile][ot] — all stores deferred
    const int swz = l15 & 7;

    #pragma unroll
    for (int t = 0; t < 4; ++t) {
        // counted wait for tile t's 4 DMAs (4 younger DMAs allowed in flight)
        if (t == 3) asm volatile("s_waitcnt vmcnt(0)" ::: "memory");
        else        asm volatile("s_waitcnt vmcnt(4)" ::: "memory");
        __builtin_amdgcn_sched_barrier(0);

        const float* sp = &xlds[wv][t & 1][0];
        f32x4 v0 = *(const f32x4*)(sp + l15 * 64 + (((2 * l4)     ^ swz) << 2));
        f32x4 v1 = *(const f32x4*)(sp + l15 * 64 + (((2 * l4 + 1) ^ swz) << 2));
        f32x4 v2 = *(const f32x4*)(sp + l15 * 64 + (((8 + 2 * l4) ^ swz) << 2));
        f32x4 v3 = *(const f32x4*)(sp + l15 * 64 + (((9 + 2 * l4) ^ swz) << 2));

        if (t < 2) {
            // slot consumed; ensure reads sampled before the refill can land
            asm volatile("s_waitcnt lgkmcnt(0)" ::: "memory");
            __builtin_amdgcn_sched_barrier(0);
            issue_tile(t + 2, t & 1);
        }

        // LN stats over the row (4 lanes share a row: xor 16, 32)
        float s = 0.f, s2 = 0.f;
        #pragma unroll
        for (int j = 0; j < 4; ++j) {
            s += v0[j] + v1[j] + v2[j] + v3[j];
            s2 += v0[j]*v0[j] + v1[j]*v1[j] + v2[j]*v2[j] + v3[j]*v3[j];
        }
        s  += __shfl_xor(s, 16, 64);  s  += __shfl_xor(s, 32, 64);
        s2 += __shfl_xor(s2, 16, 64); s2 += __shfl_xor(s2, 32, 64);
        const float mu   = s * (1.0f / 64.0f);
        const float var  = s2 * (1.0f / 64.0f) - mu * mu;
        const float rstd = rsqrtf(var + 1e-6f);

        // normalize + affine -> A fragments (bf16)   [R1 numerics]
        bf16x8 a0, a1;
        #pragma unroll
        for (int j = 0; j < 4; ++j) {
            float c1 = rstd * gk[j];
            a0[j]     = bf16_rne(v0[j] * c1 + (bk[j] - mu * c1));
            float c2 = rstd * gk[4 + j];
            a0[4 + j] = bf16_rne(v1[j] * c2 + (bk[4 + j] - mu * c2));
            float c3 = rstd * gk[8 + j];
            a1[j]     = bf16_rne(v2[j] * c3 + (bk[8 + j] - mu * c3));
            float c4 = rstd * gk[12 + j];
            a1[4 + j] = bf16_rne(v3[j] * c4 + (bk[12 + j] - mu * c4));
        }

        #pragma unroll
        for (int ot = 0; ot < 4; ++ot) {
            f32x4 acc = {0.f, 0.f, 0.f, 0.f};
            acc = __builtin_amdgcn_mfma_f32_16x16x32_bf16(a0, bfrag[ot][0], acc, 0, 0, 0);
            acc = __builtin_amdgcn_mfma_f32_16x16x32_bf16(a1, bfrag[ot][1], acc, 0, 0, 0);
            #pragma unroll
            for (int q = 0; q < 4; ++q) acc[q] += bo[ot];
            vout[t][ot] = acc;
        }
    }

    // ---- epilogue (kernel end): per channel, FULL 256 B span, sc0+sc1+nt ----
    #pragma unroll
    for (int ot = 0; ot < 4; ++ot) {
        float* base = outg + (size_t)(ot * 16 + l15) * 32768 + rr0 + l4 * 4;
        #pragma unroll
        for (int t = 0; t < 4; ++t) {
            float* dst = base + t * 16;
            asm volatile("global_store_dwordx4 %0, %1, off sc0 sc1 nt"
                         :: "v"(dst), "v"(vout[t][ot]) : "memory");
        }
    }
}

extern "C" void kernel_launch(void* const* d_in, const int* in_sizes, int n_in,
                              void* d_out, int out_size, void* d_ws, size_t ws_size,
                              hipStream_t stream) {
    const float* x     = (const float*)d_in[0];
    const float* gamma = (const float*)d_in[1];
    const float* beta  = (const float*)d_in[2];
    const float* W     = (const float*)d_in[3];
    const float* b     = (const float*)d_in[4];
    float* out = (float*)d_out;

    dim3 grid(2048), block(256);
    hipLaunchKernelGGL(gln_mfma_kernel, grid, block, 0, stream, x, gamma, beta, W, b, out);
}

// Round 31
// 49.725 us; speedup vs baseline: 1.0149x; 1.0149x over previous
//
#include <hip/hip_runtime.h>

typedef __attribute__((ext_vector_type(4))) float f32x4;
typedef __attribute__((ext_vector_type(8))) short bf16x8;

typedef const __attribute__((address_space(1))) float* gas1p;
typedef __attribute__((address_space(3))) float* las3p;

__device__ __forceinline__ short bf16_rne(float f) {
    unsigned int u = __float_as_uint(f);
    u += 0x7FFFu + ((u >> 16) & 1u);
    return (short)(u >> 16);
}

// G=16, in_g=out_g=64. rows-per-group = 32768, total rows = 524288.
// Row r: 64 contiguous floats of x; group g = r>>15.
// out[(g*64+o)*32768 + (r & 32767)].
// Wave: 64 consecutive rows = 4 tiles of 16 rows. 8192 waves = 2048 blocks x 4.
// == CHAMPION (R27, 49.0us) restored byte-for-byte. ==
// NUMERICS: R1's validated path (absmax 0.031): A = bf16(xhat*gamma+beta),
// B = bf16(W) from global loads, bias in fp32 epilogue.
// Pipeline: wave-private 3-slot LDS DMA (global_load_lds w16), counted vmcnt
// waits 8/8/4/0, lgkmcnt fence before slot-0 refill. XOR swizzle cl^(row&7).
// STORES: defer vout[4][4]; per channel FULL 256-B span, 4 adjacent
// `global_store_dwordx4 sc0 sc1 nt` at KERNEL END. WRITE = exactly |out|.
// PLATEAU NOTE (R30): 265 MB fabric traffic / 49us = 5.4 TB/s = 86% of the
// 6.29 TB/s measured copy ceiling; both streams byte-exact; occupancy cap
// (~27%) is not resource-set (invariant across VGPR 64-100, LDS 0-48KB).
// FAILED AVENUES: persistence (R11/R16/R17); register prefetch depth
// (R13/R14); channel-split (R15); LDS out-epilogue (R8); LDS W-staging (R24);
// gamma-fold (R2); nt w/o sc1 (R4/R6/R7); asm stores mid-loop (R19);
// per-tile buffer stores (R22); launch_bounds(256,8) (R23); sc0 L3-bypass
// (R25); 2-slot+W-first (R28: neutral, occupancy unmoved).

__global__ __launch_bounds__(256, 2)
void gln_mfma_kernel(const float* __restrict__ x,
                     const float* __restrict__ gamma,
                     const float* __restrict__ beta,
                     const float* __restrict__ W,
                     const float* __restrict__ bias,
                     float* __restrict__ out)
{
    __shared__ __align__(16) float xlds[4][3][1024];   // 4 waves x 3 slots x 4KB

    const int tid  = threadIdx.x;
    const int lane = tid & 63;
    const int wv   = tid >> 6;
    const int w    = blockIdx.x * 4 + wv;            // 0..8191
    const int g    = w >> 9;                         // 16 groups, 512 waves each
    const int rr0  = (w & 511) << 6;                 // row-in-group base (64 rows)

    const int l15 = lane & 15;
    const int l4  = lane >> 4;      // 0..3
    const int ks  = l4 * 8;         // k-slice base within a 32-wide K chunk

    const float* xg = x   + (size_t)g * 32768 * 64;
    float* outg     = out + (size_t)g * 64 * 32768;

    // issue tile t into slot s: 4 global_load_lds (w16), LDS linear by lane,
    // global source pre-swizzled so readback sector c is at stored c^(row&7).
    auto issue_tile = [&](int t, int s) {
        const float* tb = xg + (size_t)(rr0 + t * 16) * 64;
        #pragma unroll
        for (int j = 0; j < 4; ++j) {
            const int p   = j * 64 + lane;           // linear 16B-sector 0..255
            const int row = p >> 4;
            const int cl  = p & 15;
            const float* src = tb + row * 64 + ((cl ^ (row & 7)) << 2);
            __builtin_amdgcn_global_load_lds((gas1p)src,
                (las3p)(&xlds[wv][s][j * 256]), 16, 0, 0);
        }
    };

    // ---- prologue: issue tiles 0,1,2 (DMA latency hides under preamble) ----
    issue_tile(0, 0);
    issue_tile(1, 1);
    issue_tile(2, 2);
    __builtin_amdgcn_sched_barrier(0);

    // ---- B fragments: lane elem j = W[g][ot*16+l15][kc*32+ks+j] ----
    bf16x8 bfrag[4][2];
    {
        const float* Wg = W + (size_t)(g * 64) * 64;
        #pragma unroll
        for (int ot = 0; ot < 4; ++ot) {
            const float* wrow = Wg + (size_t)(ot * 16 + l15) * 64;
            #pragma unroll
            for (int kc = 0; kc < 2; ++kc) {
                f32x4 w0 = *(const f32x4*)(wrow + kc * 32 + ks);
                f32x4 w1 = *(const f32x4*)(wrow + kc * 32 + ks + 4);
                bf16x8 f;
                #pragma unroll
                for (int j = 0; j < 4; ++j) { f[j] = bf16_rne(w0[j]); f[j + 4] = bf16_rne(w1[j]); }
                bfrag[ot][kc] = f;
            }
        }
    }

    // ---- gamma/beta for this lane's 16 k positions ----
    float gk[16], bk[16];
    {
        const float* gp = gamma + g * 64;
        const float* bp = beta  + g * 64;
        #pragma unroll
        for (int kc = 0; kc < 2; ++kc) {
            f32x4 g0 = *(const f32x4*)(gp + kc * 32 + ks);
            f32x4 g1 = *(const f32x4*)(gp + kc * 32 + ks + 4);
            f32x4 b0 = *(const f32x4*)(bp + kc * 32 + ks);
            f32x4 b1 = *(const f32x4*)(bp + kc * 32 + ks + 4);
            #pragma unroll
            for (int j = 0; j < 4; ++j) {
                gk[kc * 8 + j] = g0[j]; gk[kc * 8 + 4 + j] = g1[j];
                bk[kc * 8 + j] = b0[j]; bk[kc * 8 + 4 + j] = b1[j];
            }
        }
    }

    float bo[4];
    #pragma unroll
    for (int ot = 0; ot < 4; ++ot) bo[ot] = bias[g * 64 + ot * 16 + l15];

    f32x4 vout[4][4];                   // [tile][ot] — all stores deferred
    const int swz = l15 & 7;

    #pragma unroll
    for (int t = 0; t < 4; ++t) {
        // wait for tile t's 4 DMAs (counted immediates; never drain younger tiles)
        if (t == 3)      asm volatile("s_waitcnt vmcnt(0)" ::: "memory");
        else if (t == 2) asm volatile("s_waitcnt vmcnt(4)" ::: "memory");
        else             asm volatile("s_waitcnt vmcnt(8)" ::: "memory");
        __builtin_amdgcn_sched_barrier(0);

        const float* sp = &xlds[wv][t % 3][0];
        f32x4 v0 = *(const f32x4*)(sp + l15 * 64 + (((2 * l4)     ^ swz) << 2));
        f32x4 v1 = *(const f32x4*)(sp + l15 * 64 + (((2 * l4 + 1) ^ swz) << 2));
        f32x4 v2 = *(const f32x4*)(sp + l15 * 64 + (((8 + 2 * l4) ^ swz) << 2));
        f32x4 v3 = *(const f32x4*)(sp + l15 * 64 + (((9 + 2 * l4) ^ swz) << 2));

        if (t == 0) {
            // slot 0 consumed; ensure the reads sampled before refill can land
            asm volatile("s_waitcnt lgkmcnt(0)" ::: "memory");
            __builtin_amdgcn_sched_barrier(0);
            issue_tile(3, 0);
        }

        // LN stats over the row (4 lanes share a row: xor 16, 32)
        float s = 0.f, s2 = 0.f;
        #pragma unroll
        for (int j = 0; j < 4; ++j) {
            s += v0[j] + v1[j] + v2[j] + v3[j];
            s2 += v0[j]*v0[j] + v1[j]*v1[j] + v2[j]*v2[j] + v3[j]*v3[j];
        }
        s  += __shfl_xor(s, 16, 64);  s  += __shfl_xor(s, 32, 64);
        s2 += __shfl_xor(s2, 16, 64); s2 += __shfl_xor(s2, 32, 64);
        const float mu   = s * (1.0f / 64.0f);
        const float var  = s2 * (1.0f / 64.0f) - mu * mu;
        const float rstd = rsqrtf(var + 1e-6f);

        // normalize + affine -> A fragments (bf16)   [R1 numerics]
        bf16x8 a0, a1;
        #pragma unroll
        for (int j = 0; j < 4; ++j) {
            float c1 = rstd * gk[j];
            a0[j]     = bf16_rne(v0[j] * c1 + (bk[j] - mu * c1));
            float c2 = rstd * gk[4 + j];
            a0[4 + j] = bf16_rne(v1[j] * c2 + (bk[4 + j] - mu * c2));
            float c3 = rstd * gk[8 + j];
            a1[j]     = bf16_rne(v2[j] * c3 + (bk[8 + j] - mu * c3));
            float c4 = rstd * gk[12 + j];
            a1[4 + j] = bf16_rne(v3[j] * c4 + (bk[12 + j] - mu * c4));
        }

        #pragma unroll
        for (int ot = 0; ot < 4; ++ot) {
            f32x4 acc = {0.f, 0.f, 0.f, 0.f};
            acc = __builtin_amdgcn_mfma_f32_16x16x32_bf16(a0, bfrag[ot][0], acc, 0, 0, 0);
            acc = __builtin_amdgcn_mfma_f32_16x16x32_bf16(a1, bfrag[ot][1], acc, 0, 0, 0);
            #pragma unroll
            for (int q = 0; q < 4; ++q) acc[q] += bo[ot];
            vout[t][ot] = acc;
        }
    }

    // ---- epilogue (kernel end): per channel, FULL 256 B span, sc0+sc1+nt ----
    #pragma unroll
    for (int ot = 0; ot < 4; ++ot) {
        float* base = outg + (size_t)(ot * 16 + l15) * 32768 + rr0 + l4 * 4;
        #pragma unroll
        for (int t = 0; t < 4; ++t) {
            float* dst = base + t * 16;
            asm volatile("global_store_dwordx4 %0, %1, off sc0 sc1 nt"
                         :: "v"(dst), "v"(vout[t][ot]) : "memory");
        }
    }
}

extern "C" void kernel_launch(void* const* d_in, const int* in_sizes, int n_in,
                              void* d_out, int out_size, void* d_ws, size_t ws_size,
                              hipStream_t stream) {
    const float* x     = (const float*)d_in[0];
    const float* gamma = (const float*)d_in[1];
    const float* beta  = (const float*)d_in[2];
    const float* W     = (const float*)d_in[3];
    const float* b     = (const float*)d_in[4];
    float* out = (float*)d_out;

    dim3 grid(2048), block(256);
    hipLaunchKernelGGL(gln_mfma_kernel, grid, block, 0, stream, x, gamma, beta, W, b, out);
}